// Round 5
// baseline (26957.245 us; speedup 1.0000x reference)
//
#include <hip/hip_runtime.h>
#include <math.h>

typedef unsigned short u16;

#define BB 2
#define LL 2048
#define DD 1024
#define HH 16
#define HDIM 64
#define SCALE 0.03125f   // 1/sqrt(1024)

#define ATTN_ELEMS ((size_t)BB * LL * DD)           // 4,194,304
#define AW_ELEMS   ((size_t)BB * HH * LL * LL)      // 134,217,728

__device__ __forceinline__ float bf2f(u16 s) {
    union { float f; unsigned u; } c; c.u = ((unsigned)s) << 16; return c.f;
}
__device__ __forceinline__ u16 f2bf(float f) {
    union { float f; unsigned u; } c; c.f = f;
    unsigned u = c.u;
    u += 0x7fffu + ((u >> 16) & 1u);
    return (u16)(u >> 16);
}

// Generic element-indexed accessors: isf32 selects fp32 vs bf16 storage.
__device__ __forceinline__ float ldany(const void* p, size_t i, int isf32) {
    return isf32 ? ((const float*)p)[i] : bf2f(((const u16*)p)[i]);
}
__device__ __forceinline__ void stany(void* p, size_t i, float v, int isf32) {
    if (isf32) ((float*)p)[i] = v; else ((u16*)p)[i] = f2bf(v);
}

// ---------------------------------------------------------------------------
// Dtype detector: view q as u16. If data is bf16, even-position u16s are real
// bf16 values of ~N(0,1) samples (exponent field in [110,140] w.p. ~1-1e-5).
// If data is fp32, even positions are low mantissa halves (uniform bits,
// plausible-exponent prob ~12%). Count over 64 evens; >=48 plausible => bf16.
__global__ void detect_kernel(const u16* __restrict__ q, int* __restrict__ flag) {
    if (threadIdx.x == 0) {
        int valid = 0;
        for (int i = 0; i < 64; ++i) {
            unsigned e = (q[2 * i] >> 7) & 0xFF;
            if (e >= 110 && e <= 140) valid++;
        }
        *flag = (valid >= 48) ? 0 : 1;   // 0 = bf16, 1 = fp32
    }
}

// ---------------------------------------------------------------------------
// Zero elements [beg, end) of out (dtype per flag), grid-stride.
__global__ __launch_bounds__(256) void zero_kernel(
    void* out, const int* __restrict__ flag, size_t beg, size_t end) {
    const int isf32 = flag ? *flag : 1;
    const size_t stride = (size_t)gridDim.x * 256;
    for (size_t i = beg + (size_t)blockIdx.x * 256 + threadIdx.x; i < end; i += stride)
        stany(out, i, 0.f, isf32);
}

// ---------------------------------------------------------------------------
// One block (256 threads) per (b, h, query-row).
// ctx_mode: 1 => ctx buffer is always fp32 (workspace); 0 => ctx dtype follows flag.
__global__ __launch_bounds__(256) void attn_row_kernel(
    const void* __restrict__ q, const void* __restrict__ k, const void* __restrict__ v,
    void* __restrict__ out,      // whole d_out; aw region begins at ATTN_ELEMS
    void* __restrict__ ctx, int ctx_mode,
    const int* __restrict__ flag)
{
    const int isf32 = flag ? *flag : 1;
    const int ctx_f32 = ctx_mode ? 1 : isf32;

    const int bid = blockIdx.x;            // ((b*HH)+h)*LL + qr
    const int qr  = bid & (LL - 1);
    const int h   = (bid >> 11) & (HH - 1);
    const int b   = bid >> 15;
    const int t   = threadIdx.x;

    __shared__ float scores[LL];           // 8 KB
    __shared__ float rv[4];
    __shared__ int   ri[4];
    __shared__ float topv[8];
    __shared__ int   topi[8];
    __shared__ float wts[8];

    // q row -> registers
    float qreg[64];
    {
        const size_t qbase = ((size_t)(b * LL + qr)) * DD + (size_t)h * HDIM;
        #pragma unroll
        for (int d = 0; d < 64; ++d) qreg[d] = ldany(q, qbase + d, isf32);
    }

    // scores: thread t covers cols {t, t+256, ..., t+1792}
    for (int cc = 0; cc < 8; ++cc) {
        const int col = cc * 256 + t;
        const size_t kbase = ((size_t)(b * LL + col)) * DD + (size_t)h * HDIM;
        float acc = 0.f;
        #pragma unroll
        for (int d = 0; d < 64; ++d)
            acc = fmaf(qreg[d], ldany(k, kbase + d, isf32), acc);
        scores[col] = acc * SCALE;
    }
    __syncthreads();

    // top-8 by successive argmax (value desc, then index asc — lax.top_k order)
    for (int s = 0; s < 8; ++s) {
        float bv = -INFINITY; int bi = 0;
        for (int cc = 0; cc < 8; ++cc) {
            int col = cc * 256 + t;
            float sv = scores[col];
            if (sv > bv) { bv = sv; bi = col; }   // ascending cols: '>' keeps lowest idx
        }
        #pragma unroll
        for (int off = 32; off >= 1; off >>= 1) {
            float ov = __shfl_down(bv, off);
            int   oi = __shfl_down(bi, off);
            if (ov > bv || (ov == bv && oi < bi)) { bv = ov; bi = oi; }
        }
        if ((t & 63) == 0) { rv[t >> 6] = bv; ri[t >> 6] = bi; }
        __syncthreads();
        if (t == 0) {
            float fv = rv[0]; int fi = ri[0];
            #pragma unroll
            for (int j = 1; j < 4; ++j)
                if (rv[j] > fv || (rv[j] == fv && ri[j] < fi)) { fv = rv[j]; fi = ri[j]; }
            fi = (fi >= 0 && fi < LL) ? fi : 0;   // crash-guard (only reachable on corrupt data)
            topv[s] = fv; topi[s] = fi;
            scores[fi] = -INFINITY;
        }
        __syncthreads();
    }

    // softmax over the 8 + scatter into attn_weights region of out
    if (t == 0) {
        float m = topv[0];
        float e0[8]; float sum = 0.f;
        #pragma unroll
        for (int s = 0; s < 8; ++s) { e0[s] = __expf(topv[s] - m); sum += e0[s]; }
        float inv = 1.0f / sum;
        const size_t rowbase = ATTN_ELEMS + (size_t)bid * LL;
        #pragma unroll
        for (int s = 0; s < 8; ++s) {
            float w8 = e0[s] * inv;
            wts[s] = w8;
            stany(out, rowbase + (size_t)topi[s], w8, isf32);
        }
    }
    __syncthreads();

    // context row (64 dims)
    if (t < 64) {
        float acc = 0.f;
        #pragma unroll
        for (int s = 0; s < 8; ++s)
            acc += wts[s] * ldany(v, ((size_t)(b * LL + topi[s])) * DD + (size_t)h * HDIM + t, isf32);
        stany(ctx, ((size_t)(b * LL + qr)) * DD + (size_t)h * HDIM + t, acc, ctx_f32);
    }
}

// ---------------------------------------------------------------------------
// Projection (workspace path): ctx is fp32 in d_ws, out does not alias.
// One thread per output element; grid = ATTN_ELEMS/256 = 16384 blocks.
__global__ __launch_bounds__(256) void linear_ws_kernel(
    const float* __restrict__ ctx, const void* __restrict__ w,
    const void* __restrict__ bias, void* __restrict__ out,
    const int* __restrict__ flag)
{
    const int isf32 = flag ? *flag : 1;
    const size_t i = (size_t)blockIdx.x * 256 + threadIdx.x;
    const size_t m = i >> 10;
    const size_t n = i & 1023;
    float acc = ldany(bias, n, isf32);
    const size_t cb = m * DD, wb = n * DD;
    for (int kk = 0; kk < DD; ++kk)
        acc = fmaf(ctx[cb + kk], ldany(w, wb + kk, isf32), acc);
    stany(out, i, acc, isf32);
}

// Projection (in-place fallback): ctx lives in out[0..ATTN) in io dtype.
// 16 rows per block staged to LDS (64 KB as fp32) before any write.
__global__ __launch_bounds__(256) void linear_inplace_kernel(
    void* io, const void* __restrict__ w, const void* __restrict__ bias,
    const int* __restrict__ flag)
{
    __shared__ float a_lds[16][1024];   // 64 KB
    const int isf32 = flag ? *flag : 1;
    const int t = threadIdx.x;
    const size_t m0 = (size_t)blockIdx.x * 16;

    for (int i = 0; i < 64; ++i) {
        int id = i * 256 + t;
        int r = id >> 10, c = id & 1023;
        a_lds[r][c] = ldany(io, (m0 + r) * DD + c, isf32);
    }
    __syncthreads();

    for (int i = 0; i < 64; ++i) {
        int id = i * 256 + t;
        int r = id >> 10, n = id & 1023;
        float acc = ldany(bias, (size_t)n, isf32);
        const size_t wb = (size_t)n * DD;
        for (int kk = 0; kk < DD; ++kk)
            acc = fmaf(a_lds[r][kk], ldany(w, wb + kk, isf32), acc);
        stany(io, (m0 + r) * DD + n, acc, isf32);
    }
}

extern "C" void kernel_launch(void* const* d_in, const int* in_sizes, int n_in,
                              void* d_out, int out_size, void* d_ws, size_t ws_size,
                              hipStream_t stream) {
    const void* q    = d_in[0];
    const void* k    = d_in[1];
    const void* v    = d_in[2];
    const void* w    = d_in[3];
    const void* bias = d_in[4];

    // ws layout: [0,256) dtype flag; [256, 256+16MB) fp32 ctx (if it fits)
    int*   flag = (d_ws && ws_size >= 256) ? (int*)d_ws : nullptr;
    const bool use_ws = (d_ws && ws_size >= ATTN_ELEMS * sizeof(float) + 256);
    float* ctx  = use_ws ? (float*)((char*)d_ws + 256) : nullptr;

    if (flag) detect_kernel<<<1, 64, 0, stream>>>((const u16*)q, flag);

    // zero the attn_weights element range [ATTN, min(ATTN+AW, out_size))
    {
        size_t zend = ATTN_ELEMS + AW_ELEMS;
        if ((size_t)out_size < zend) zend = (size_t)out_size;
        if (zend > ATTN_ELEMS)
            zero_kernel<<<4096, 256, 0, stream>>>(d_out, flag, ATTN_ELEMS, zend);
    }

    attn_row_kernel<<<BB * HH * LL, 256, 0, stream>>>(
        q, k, v, d_out,
        use_ws ? (void*)ctx : d_out, use_ws ? 1 : 0, flag);

    if (use_ws) {
        linear_ws_kernel<<<ATTN_ELEMS / 256, 256, 0, stream>>>(ctx, w, bias, d_out, flag);
    } else {
        linear_inplace_kernel<<<(BB * LL) / 16, 256, 0, stream>>>(d_out, w, bias, flag);
    }
}

// Round 6
// 2110.073 us; speedup vs baseline: 12.7755x; 12.7755x over previous
//
#include <hip/hip_runtime.h>
#include <math.h>

#define BB 2
#define LL 2048
#define DD 1024
#define HH 16
#define HDIM 64
#define SCALE 0.03125f   // 1/sqrt(1024)

#define ATTN_ELEMS ((size_t)BB * LL * DD)           // 4,194,304 fp32
#define AW_ELEMS   ((size_t)BB * HH * LL * LL)      // 134,217,728 fp32

typedef __attribute__((ext_vector_type(4))) float f4;

// Branchless stable insert of (cv,ci) into descending-sorted 8-list.
// Precondition: cv > tv[7]. Candidates arrive in ascending index order,
// strict '>' keeps the earlier index on ties (lax.top_k semantics).
__device__ __forceinline__ void insert8(float (&tv)[8], int (&ti)[8], float cv, int ci) {
    bool g0 = cv > tv[0], g1 = cv > tv[1], g2 = cv > tv[2], g3 = cv > tv[3],
         g4 = cv > tv[4], g5 = cv > tv[5], g6 = cv > tv[6];
    tv[7] = g6 ? tv[6] : cv;                 ti[7] = g6 ? ti[6] : ci;
    tv[6] = g5 ? tv[5] : (g6 ? cv : tv[6]);  ti[6] = g5 ? ti[5] : (g6 ? ci : ti[6]);
    tv[5] = g4 ? tv[4] : (g5 ? cv : tv[5]);  ti[5] = g4 ? ti[4] : (g5 ? ci : ti[5]);
    tv[4] = g3 ? tv[3] : (g4 ? cv : tv[4]);  ti[4] = g3 ? ti[3] : (g4 ? ci : ti[4]);
    tv[3] = g2 ? tv[2] : (g3 ? cv : tv[3]);  ti[3] = g2 ? ti[2] : (g3 ? ci : ti[3]);
    tv[2] = g1 ? tv[1] : (g2 ? cv : tv[2]);  ti[2] = g1 ? ti[1] : (g2 ? ci : ti[2]);
    tv[1] = g0 ? tv[0] : (g1 ? cv : tv[1]);  ti[1] = g0 ? ti[0] : (g1 ? ci : ti[1]);
    tv[0] = g0 ? cv : tv[0];                 ti[0] = g0 ? ci : ti[0];
}

__device__ __forceinline__ float dot4acc(f4 a, f4 b, float acc) {
    acc = fmaf(a[0], b[0], acc);
    acc = fmaf(a[1], b[1], acc);
    acc = fmaf(a[2], b[2], acc);
    acc = fmaf(a[3], b[3], acc);
    return acc;
}

// ---------------------------------------------------------------------------
// Fused attention: one block per (b, h, 16-query tile). 256 threads.
// - zero-fills this block's 16 aw rows (spread over the K loop)
// - fp32 LDS-tiled scoring (16 K-tiles of 128 rows)
// - per-thread top-8 over a 64-candidate stream (2 rows x 4 col-streams)
// - 2-stage merge -> exact top-8 per row -> softmax -> scatter -> context
__global__ __launch_bounds__(256) void attn_kernel(
    const float* __restrict__ q, const float* __restrict__ k, const float* __restrict__ v,
    float* __restrict__ aw, float* __restrict__ ctx)
{
    const int bid = blockIdx.x;          // b*HH*128 + h*128 + qt
    const int qt  = bid & 127;
    const int h   = (bid >> 7) & 15;
    const int b   = bid >> 11;
    const int t   = threadIdx.x;

    __shared__ float q_lds[16][68];      // 4,352 B
    __shared__ float k_lds[128 * 68];    // 34,816 B (aliased as merge space later)
    __shared__ float s2v[16][8][8];      // 4 KB
    __shared__ int   s2i[16][8][8];      // 4 KB
    __shared__ float wrow[16][8];
    __shared__ int   wix[16][8];

    float* mv = k_lds;                   // [16 rows][32 streams][8]  (16 KB)
    int*   mi = (int*)(k_lds + 4096);    // [16 rows][32 streams][8]  (16 KB)

    const float* kbase = k + ((size_t)b * LL) * DD + h * HDIM;
    f4* awz = (f4*)(aw + (((size_t)(b * HH + h) * LL) + (size_t)qt * 16) * LL);
    const f4 zero4 = {0.f, 0.f, 0.f, 0.f};

    // stage Q tile: 16 rows x 64 dims = 256 f4, one per thread
    {
        int row = t >> 4, seg = t & 15;
        *(f4*)&q_lds[row][seg * 4] =
            *(const f4*)(q + ((size_t)(b * LL + qt * 16 + row)) * DD + h * HDIM + seg * 4);
    }

    const int rp = t >> 5;               // 0..7  -> rows 2rp, 2rp+1
    const int r0 = rp * 2, r1 = r0 + 1;
    const int cl = t & 31;               // col stream

    float tvA[8], tvB[8]; int tiA[8], tiB[8];
    #pragma unroll
    for (int s = 0; s < 8; ++s) { tvA[s] = -INFINITY; tvB[s] = -INFINITY; tiA[s] = 0; tiB[s] = 0; }

    for (int tt = 0; tt < 16; ++tt) {
        __syncthreads();                 // k_lds reads of prev tile done
        // stage K tile: 128 rows x 64 dims = 2048 f4, 8 per thread (coalesced)
        #pragma unroll
        for (int i = 0; i < 8; ++i) {
            int id = i * 256 + t;
            int row = id >> 4, seg = id & 15;
            *(f4*)&k_lds[row * 68 + seg * 4] =
                *(const f4*)(kbase + (size_t)(tt * 128 + row) * DD + seg * 4);
        }
        // spread the aw zero-fill: 8192 f4 total over 16 tiles -> 2 per thread
        awz[tt * 512 + t]       = zero4;
        awz[tt * 512 + 256 + t] = zero4;
        __syncthreads();

        // compute 16x128 scores: thread = (2 rows, 4 cols: cl+32j)
        float sA[4] = {0.f,0.f,0.f,0.f}, sB[4] = {0.f,0.f,0.f,0.f};
        for (int d4 = 0; d4 < 16; ++d4) {
            f4 qa = *(const f4*)&q_lds[r0][d4 * 4];
            f4 qb = *(const f4*)&q_lds[r1][d4 * 4];
            #pragma unroll
            for (int j = 0; j < 4; ++j) {
                f4 kv = *(const f4*)&k_lds[(cl + 32 * j) * 68 + d4 * 4];
                sA[j] = dot4acc(qa, kv, sA[j]);
                sB[j] = dot4acc(qb, kv, sB[j]);
            }
        }
        #pragma unroll
        for (int j = 0; j < 4; ++j) {
            int ci = tt * 128 + cl + 32 * j;
            float cv = sA[j] * SCALE;
            if (cv > tvA[7]) insert8(tvA, tiA, cv, ci);
            cv = sB[j] * SCALE;
            if (cv > tvB[7]) insert8(tvB, tiB, cv, ci);
        }
    }

    __syncthreads();                     // all k_lds reads done; alias as merge space
    #pragma unroll
    for (int s = 0; s < 8; ++s) {
        mv[(r0 * 32 + cl) * 8 + s] = tvA[s]; mi[(r0 * 32 + cl) * 8 + s] = tiA[s];
        mv[(r1 * 32 + cl) * 8 + s] = tvB[s]; mi[(r1 * 32 + cl) * 8 + s] = tiB[s];
    }
    __syncthreads();

    // stage 1: 128 threads, each 4-way merges streams {4p..4p+3} of row r -> top-8
    if (t < 128) {
        int r = t >> 3, p = t & 7;
        const float* L0 = &mv[(r * 32 + p * 4 + 0) * 8]; const int* I0 = &mi[(r * 32 + p * 4 + 0) * 8];
        const float* L1 = &mv[(r * 32 + p * 4 + 1) * 8]; const int* I1 = &mi[(r * 32 + p * 4 + 1) * 8];
        const float* L2 = &mv[(r * 32 + p * 4 + 2) * 8]; const int* I2 = &mi[(r * 32 + p * 4 + 2) * 8];
        const float* L3 = &mv[(r * 32 + p * 4 + 3) * 8]; const int* I3 = &mi[(r * 32 + p * 4 + 3) * 8];
        int p0 = 0, p1 = 0, p2 = 0, p3 = 0;
        #pragma unroll
        for (int s = 0; s < 8; ++s) {
            float v0 = L0[p0], v1 = L1[p1], v2 = L2[p2], v3 = L3[p3];
            int   i0 = I0[p0], i1 = I1[p1], i2 = I2[p2], i3 = I3[p3];
            float bv = v0; int bi = i0; int bc = 0;
            if (v1 > bv || (v1 == bv && i1 < bi)) { bv = v1; bi = i1; bc = 1; }
            if (v2 > bv || (v2 == bv && i2 < bi)) { bv = v2; bi = i2; bc = 2; }
            if (v3 > bv || (v3 == bv && i3 < bi)) { bv = v3; bi = i3; bc = 3; }
            p0 += (bc == 0); p1 += (bc == 1); p2 += (bc == 2); p3 += (bc == 3);
            s2v[r][p][s] = bv; s2i[r][p][s] = bi;
        }
    }
    __syncthreads();

    // stage 2: 16 threads, 8-way merge -> global top-8, softmax, scatter
    if (t < 16) {
        int r = t;
        int pp[8] = {0,0,0,0,0,0,0,0};
        float fv[8]; int fi[8];
        #pragma unroll
        for (int s = 0; s < 8; ++s) {
            float bv = -INFINITY; int bi = 0x7fffffff; int bc = 0;
            #pragma unroll
            for (int l = 0; l < 8; ++l) {
                float hv = s2v[r][l][pp[l]]; int hi = s2i[r][l][pp[l]];
                if (hv > bv || (hv == bv && hi < bi)) { bv = hv; bi = hi; bc = l; }
            }
            #pragma unroll
            for (int l = 0; l < 8; ++l) pp[l] += (bc == l);
            fv[s] = bv; fi[s] = bi & (LL - 1);
        }
        float m = fv[0];
        float e0[8]; float sum = 0.f;
        #pragma unroll
        for (int s = 0; s < 8; ++s) { e0[s] = __expf(fv[s] - m); sum += e0[s]; }
        float inv = 1.0f / sum;
        float* awrow = aw + (((size_t)(b * HH + h) * LL) + (size_t)qt * 16 + r) * LL;
        #pragma unroll
        for (int s = 0; s < 8; ++s) {
            float w8 = e0[s] * inv;
            awrow[fi[s]] = w8;
            wrow[r][s] = w8; wix[r][s] = fi[s];
        }
    }
    __syncthreads();

    // context: 16 rows x 64 dims = 256 f4, one per thread
    {
        int row = t >> 4, seg = t & 15;
        f4 acc = {0.f, 0.f, 0.f, 0.f};
        #pragma unroll
        for (int s = 0; s < 8; ++s) {
            float ws = wrow[row][s];
            f4 vv = *(const f4*)(v + ((size_t)(b * LL + wix[row][s])) * DD + h * HDIM + seg * 4);
            acc[0] = fmaf(ws, vv[0], acc[0]);
            acc[1] = fmaf(ws, vv[1], acc[1]);
            acc[2] = fmaf(ws, vv[2], acc[2]);
            acc[3] = fmaf(ws, vv[3], acc[3]);
        }
        *(f4*)(ctx + ((size_t)(b * LL + qt * 16 + row)) * DD + h * HDIM + seg * 4) = acc;
    }
}

// ---------------------------------------------------------------------------
// Projection (workspace path): out[m][n] = sum_k ctx[m][k]*w[n][k] + bias[n].
// 64x64 tile per block, 16x16 thread grid, strided 4x4 micro-tiles.
__global__ __launch_bounds__(256) void linear_ws_kernel(
    const float* __restrict__ ctx, const float* __restrict__ w,
    const float* __restrict__ bias, float* __restrict__ out)
{
    __shared__ float a_lds[64][68];
    __shared__ float b_lds[64][68];
    const int bidx = blockIdx.x;
    const int nb = bidx & 15, mb = bidx >> 4;
    const int t = threadIdx.x;
    const int ty = t >> 4, tx = t & 15;

    float acc[4][4] = {{0.f}};
    for (int kc = 0; kc < 16; ++kc) {
        __syncthreads();
        #pragma unroll
        for (int i = 0; i < 4; ++i) {
            int id = i * 256 + t;
            int row = id >> 4, seg = id & 15;
            *(f4*)&a_lds[row][seg * 4] =
                *(const f4*)(ctx + (size_t)(mb * 64 + row) * DD + kc * 64 + seg * 4);
            *(f4*)&b_lds[row][seg * 4] =
                *(const f4*)(w + (size_t)(nb * 64 + row) * DD + kc * 64 + seg * 4);
        }
        __syncthreads();
        for (int k4 = 0; k4 < 16; ++k4) {
            f4 av[4], bv[4];
            #pragma unroll
            for (int i = 0; i < 4; ++i) av[i] = *(const f4*)&a_lds[ty + 16 * i][k4 * 4];
            #pragma unroll
            for (int j = 0; j < 4; ++j) bv[j] = *(const f4*)&b_lds[tx + 16 * j][k4 * 4];
            #pragma unroll
            for (int i = 0; i < 4; ++i)
                #pragma unroll
                for (int j = 0; j < 4; ++j)
                    acc[i][j] = dot4acc(av[i], bv[j], acc[i][j]);
        }
    }
    #pragma unroll
    for (int j = 0; j < 4; ++j) {
        int col = nb * 64 + tx + 16 * j;
        float bb = bias[col];
        #pragma unroll
        for (int i = 0; i < 4; ++i)
            out[(size_t)(mb * 64 + ty + 16 * i) * DD + col] = acc[i][j] + bb;
    }
}

// Projection (in-place fallback): ctx lives in out[0..ATTN). 8 rows per block,
// fully staged to LDS before any write; row-partitioned grid -> no hazard.
__global__ __launch_bounds__(256) void linear_inplace_kernel(
    float* io, const float* __restrict__ w, const float* __restrict__ bias)
{
    __shared__ float a_lds[8][1028];   // 32,896 B
    __shared__ float w_lds[64][68];    // 17,408 B
    const int t = threadIdx.x;
    const int m0 = blockIdx.x * 8;

    #pragma unroll
    for (int i = 0; i < 8; ++i) {
        int id = i * 256 + t;
        int r = id >> 8, seg = id & 255;
        *(f4*)&a_lds[r][seg * 4] = *(const f4*)(io + (size_t)(m0 + r) * DD + seg * 4);
    }

    const int row = t >> 5;        // 0..7
    const int tx  = t & 31;
    for (int nb = 0; nb < 16; ++nb) {
        float acc0 = 0.f, acc1 = 0.f;     // cols nb*64+tx, nb*64+tx+32
        for (int kc = 0; kc < 16; ++kc) {
            __syncthreads();
            #pragma unroll
            for (int i = 0; i < 4; ++i) {
                int id = i * 256 + t;
                int r = id >> 4, seg = id & 15;
                *(f4*)&w_lds[r][seg * 4] =
                    *(const f4*)(w + (size_t)(nb * 64 + r) * DD + kc * 64 + seg * 4);
            }
            __syncthreads();
            for (int k4 = 0; k4 < 16; ++k4) {
                f4 av = *(const f4*)&a_lds[row][kc * 64 + k4 * 4];
                f4 w0 = *(const f4*)&w_lds[tx][k4 * 4];
                f4 w1 = *(const f4*)&w_lds[tx + 32][k4 * 4];
                acc0 = dot4acc(av, w0, acc0);
                acc1 = dot4acc(av, w1, acc1);
            }
        }
        io[(size_t)(m0 + row) * DD + nb * 64 + tx]      = acc0 + bias[nb * 64 + tx];
        io[(size_t)(m0 + row) * DD + nb * 64 + tx + 32] = acc1 + bias[nb * 64 + tx + 32];
    }
}

extern "C" void kernel_launch(void* const* d_in, const int* in_sizes, int n_in,
                              void* d_out, int out_size, void* d_ws, size_t ws_size,
                              hipStream_t stream) {
    const float* q    = (const float*)d_in[0];
    const float* k    = (const float*)d_in[1];
    const float* v    = (const float*)d_in[2];
    const float* w    = (const float*)d_in[3];
    const float* bias = (const float*)d_in[4];

    float* out = (float*)d_out;                      // attn_out [B*L*D]
    float* aw  = out + ATTN_ELEMS;                   // attn_weights [B*H*L*L]

    const bool use_ws = (d_ws != nullptr) && (ws_size >= ATTN_ELEMS * sizeof(float));
    float* ctx = use_ws ? (float*)d_ws : out;

    attn_kernel<<<BB * HH * 128, 256, 0, stream>>>(q, k, v, aw, ctx);
    if (use_ws) {
        linear_ws_kernel<<<(BB * LL / 64) * (DD / 64), 256, 0, stream>>>(ctx, w, bias, out);
    } else {
        linear_inplace_kernel<<<BB * LL / 8, 256, 0, stream>>>(out, w, bias);
    }
}

// Round 9
// 883.826 us; speedup vs baseline: 30.5006x; 2.3874x over previous
//
#include <hip/hip_runtime.h>
#include <math.h>

#define BB 2
#define LL 2048
#define DD 1024
#define HH 16
#define SCALE 0.03125f   // 1/sqrt(1024)

#define ATTN_ELEMS ((size_t)BB * LL * DD)           // 4,194,304 fp32

typedef unsigned short u16;
typedef __attribute__((ext_vector_type(8))) short bf16x8;
typedef __attribute__((ext_vector_type(4))) float f32x4;

__device__ __forceinline__ u16 f2bf_rne(float f) {
    union { float f; unsigned u; } c; c.f = f;
    unsigned u = c.u;
    u += 0x7fffu + ((u >> 16) & 1u);
    return (u16)(u >> 16);
}

// fp32 -> bf16 hi (truncate) + bf16 lo (RNE of residual); x ≈ hi+lo, |err| ≲ 2^-17|x|
__device__ __forceinline__ void splitbf(float x, short& h, short& l) {
    union { float f; unsigned u; } c; c.f = x;
    unsigned uh = c.u & 0xFFFF0000u;
    h = (short)(uh >> 16);
    union { unsigned u; float f; } ch; ch.u = uh;
    l = (short)f2bf_rne(x - ch.f);
}

// Branchless stable insert of (cv,ci) into descending-sorted 8-list.
// Precondition: cv > tv[7]. Candidates arrive in ascending index order.
__device__ __forceinline__ void insert8(float (&tv)[8], int (&ti)[8], float cv, int ci) {
    bool g0 = cv > tv[0], g1 = cv > tv[1], g2 = cv > tv[2], g3 = cv > tv[3],
         g4 = cv > tv[4], g5 = cv > tv[5], g6 = cv > tv[6];
    tv[7] = g6 ? tv[6] : cv;                 ti[7] = g6 ? ti[6] : ci;
    tv[6] = g5 ? tv[5] : (g6 ? cv : tv[6]);  ti[6] = g5 ? ti[5] : (g6 ? ci : ti[6]);
    tv[5] = g4 ? tv[4] : (g5 ? cv : tv[5]);  ti[5] = g4 ? ti[4] : (g5 ? ci : ti[5]);
    tv[4] = g3 ? tv[3] : (g4 ? cv : tv[4]);  ti[4] = g3 ? ti[3] : (g4 ? ci : ti[4]);
    tv[3] = g2 ? tv[2] : (g3 ? cv : tv[3]);  ti[3] = g2 ? ti[2] : (g3 ? ci : ti[3]);
    tv[2] = g1 ? tv[1] : (g2 ? cv : tv[2]);  ti[2] = g1 ? ti[1] : (g2 ? ci : ti[2]);
    tv[1] = g0 ? tv[0] : (g1 ? cv : tv[1]);  ti[1] = g0 ? ti[0] : (g1 ? ci : ti[1]);
    tv[0] = g0 ? cv : tv[0];                 ti[0] = g0 ? ci : ti[0];
}

// Merge four descending-sorted 8-lists -> top-8 (value desc, index asc on ties).
__device__ __forceinline__ void merge4(
    const float* v0, const int* i0, const float* v1, const int* i1,
    const float* v2, const int* i2, const float* v3, const int* i3,
    float* ov, int* oi)
{
    int p0 = 0, p1 = 0, p2 = 0, p3 = 0;
    #pragma unroll
    for (int s = 0; s < 8; ++s) {
        float a0 = v0[p0], a1 = v1[p1], a2 = v2[p2], a3 = v3[p3];
        int   b0 = i0[p0], b1 = i1[p1], b2 = i2[p2], b3 = i3[p3];
        float bv = a0; int bi = b0; int bc = 0;
        if (a1 > bv || (a1 == bv && b1 < bi)) { bv = a1; bi = b1; bc = 1; }
        if (a2 > bv || (a2 == bv && b2 < bi)) { bv = a2; bi = b2; bc = 2; }
        if (a3 > bv || (a3 == bv && b3 < bi)) { bv = a3; bi = b3; bc = 3; }
        p0 += (bc == 0); p1 += (bc == 1); p2 += (bc == 2); p3 += (bc == 3);
        ov[s] = bv; oi[s] = bi;
    }
}

// ---------------------------------------------------------------------------
// Fused attention: one block per (b, h, 64-query tile). 256 threads = 4 waves.
// MFMA (split-bf16) scores select top-12 candidates per row; candidates are
// rescored with exact sequential fp32 (matching the R5/R6 passing numerics),
// then top-8 + softmax + scatter + context.
__global__ __launch_bounds__(256) void attn_kernel(
    const float* __restrict__ q, const float* __restrict__ k, const float* __restrict__ v,
    float* __restrict__ aw, float* __restrict__ ctx)
{
    const int bid  = blockIdx.x;
    const int qt   = bid & 31;
    const int h    = (bid >> 5) & 15;
    const int b    = bid >> 9;
    const int t    = threadIdx.x;
    const int wv   = t >> 6;
    const int lane = t & 63;
    const int li   = lane & 15;
    const int quad = lane >> 4;

    __shared__ __align__(16) char smA[32768];   // khi+klo, later mv+mi
    __shared__ float s2v[32][4][8];
    __shared__ int   s2i[32][4][8];
    __shared__ int   cidx[32][12];
    __shared__ float cs[32][12];
    __shared__ float wrow[64][8];
    __shared__ int   wix[64][8];
    u16* khi = (u16*)smA;
    u16* klo = (u16*)(smA + 16384);

    const float* kbase = k + ((size_t)b * LL) * DD + h * 64;
    f32x4* awz = (f32x4*)(aw + (((size_t)(b * HH + h) * LL) + (size_t)qt * 64) * LL);
    const f32x4 zero4 = {0.f, 0.f, 0.f, 0.f};

    bf16x8 qh0, ql0, qh1, ql1;
    {
        const float* qrow = q + ((size_t)(b * LL + qt * 64 + wv * 16 + li)) * DD + h * 64;
        float x[8];
        *(f32x4*)x       = *(const f32x4*)(qrow + quad * 8);
        *(f32x4*)(x + 4) = *(const f32x4*)(qrow + quad * 8 + 4);
        #pragma unroll
        for (int e = 0; e < 8; ++e) { short hh, ll; splitbf(x[e], hh, ll); qh0[e] = hh; ql0[e] = ll; }
        *(f32x4*)x       = *(const f32x4*)(qrow + 32 + quad * 8);
        *(f32x4*)(x + 4) = *(const f32x4*)(qrow + 32 + quad * 8 + 4);
        #pragma unroll
        for (int e = 0; e < 8; ++e) { short hh, ll; splitbf(x[e], hh, ll); qh1[e] = hh; ql1[e] = ll; }
    }

    float tv[4][8]; int tix[4][8];
    #pragma unroll
    for (int r = 0; r < 4; ++r)
        #pragma unroll
        for (int s = 0; s < 8; ++s) { tv[r][s] = -INFINITY; tix[r][s] = 0; }

    for (int iter = 0; iter < 16; ++iter) {
        __syncthreads();
        #pragma unroll
        for (int j = 0; j < 4; ++j) {
            int f   = j * 256 + t;
            int col = f >> 3;
            int c   = (f >> 2) & 1;
            int qd  = f & 3;
            const float* src = kbase + (size_t)(iter * 128 + col) * DD + c * 32 + qd * 8;
            float x[8];
            *(f32x4*)x       = *(const f32x4*)src;
            *(f32x4*)(x + 4) = *(const f32x4*)(src + 4);
            bf16x8 h8, l8;
            #pragma unroll
            for (int e = 0; e < 8; ++e) { short hh, ll; splitbf(x[e], hh, ll); h8[e] = hh; l8[e] = ll; }
            int off = (((col >> 4) * 2 + c) << 9) + (qd << 7) + ((col & 15) << 3);
            *(bf16x8*)&khi[off] = h8;
            *(bf16x8*)&klo[off] = l8;
        }
        #pragma unroll
        for (int i = 0; i < 8; ++i) awz[iter * 2048 + i * 256 + t] = zero4;
        __syncthreads();

        #pragma unroll
        for (int s = 0; s < 8; ++s) {
            int fo = s << 10;
            bf16x8 kh0 = *(bf16x8*)&khi[fo + (lane << 3)];
            bf16x8 kh1 = *(bf16x8*)&khi[fo + 512 + (lane << 3)];
            bf16x8 kl0 = *(bf16x8*)&klo[fo + (lane << 3)];
            bf16x8 kl1 = *(bf16x8*)&klo[fo + 512 + (lane << 3)];
            f32x4 c4 = {0.f, 0.f, 0.f, 0.f};
            c4 = __builtin_amdgcn_mfma_f32_16x16x32_bf16(qh0, kh0, c4, 0, 0, 0);
            c4 = __builtin_amdgcn_mfma_f32_16x16x32_bf16(qh1, kh1, c4, 0, 0, 0);
            c4 = __builtin_amdgcn_mfma_f32_16x16x32_bf16(qh0, kl0, c4, 0, 0, 0);
            c4 = __builtin_amdgcn_mfma_f32_16x16x32_bf16(qh1, kl1, c4, 0, 0, 0);
            c4 = __builtin_amdgcn_mfma_f32_16x16x32_bf16(ql0, kh0, c4, 0, 0, 0);
            c4 = __builtin_amdgcn_mfma_f32_16x16x32_bf16(ql1, kh1, c4, 0, 0, 0);
            int ci = iter * 128 + s * 16 + li;
            #pragma unroll
            for (int r = 0; r < 4; ++r) {
                float cv = c4[r] * SCALE;
                if (cv > tv[r][7]) insert8(tv[r], tix[r], cv, ci);
            }
        }
    }

    float* mv = (float*)smA;
    int*   mi = (int*)(smA + 16384);
    for (int bb = 0; bb < 2; ++bb) {
        __syncthreads();
        if ((wv >> 1) == bb) {
            int rl0 = (wv & 1) * 16 + quad * 4;
            #pragma unroll
            for (int r = 0; r < 4; ++r) {
                int base = (rl0 + r) * 128 + li * 8;
                #pragma unroll
                for (int s = 0; s < 8; ++s) { mv[base + s] = tv[r][s]; mi[base + s] = tix[r][s]; }
            }
        }
        __syncthreads();
        // stage 1: 128 threads: 4-way merge of 4 streams -> top-8 each
        if (t < 128) {
            int rr = t >> 2, p = t & 3;
            int base = rr * 128 + p * 32;
            merge4(&mv[base], &mi[base], &mv[base + 8], &mi[base + 8],
                   &mv[base + 16], &mi[base + 16], &mv[base + 24], &mi[base + 24],
                   s2v[rr][p], s2i[rr][p]);
        }
        __syncthreads();
        // stage 2: MFMA top-12 candidate indices per row
        if (t < 32) {
            int rr = t;
            int pp[4] = {0, 0, 0, 0};
            #pragma unroll
            for (int s = 0; s < 12; ++s) {
                float bv = -INFINITY; int bi = 0x7fffffff; int bc = 0;
                #pragma unroll
                for (int l = 0; l < 4; ++l) {
                    if (pp[l] < 8) {
                        float hv = s2v[rr][l][pp[l]]; int hi2 = s2i[rr][l][pp[l]];
                        if (hv > bv || (hv == bv && hi2 < bi)) { bv = hv; bi = hi2; bc = l; }
                    }
                }
                pp[bc] += 1;
                cidx[rr][s] = bi;
            }
        }
        __syncthreads();
        // rescore the 12 candidates per row in exact sequential fp32
        for (int task = t; task < 384; task += 256) {
            int row = task / 12, c = task - row * 12;
            const float* qp = q + ((size_t)(b * LL + qt * 64 + bb * 32 + row)) * DD + h * 64;
            const float* kp = k + ((size_t)(b * LL + cidx[row][c])) * DD + h * 64;
            float acc = 0.f;
            for (int d4 = 0; d4 < 16; ++d4) {
                f32x4 qa = *(const f32x4*)(qp + d4 * 4);
                f32x4 ka = *(const f32x4*)(kp + d4 * 4);
                acc = fmaf(qa[0], ka[0], acc);
                acc = fmaf(qa[1], ka[1], acc);
                acc = fmaf(qa[2], ka[2], acc);
                acc = fmaf(qa[3], ka[3], acc);
            }
            cs[row][c] = acc * SCALE;
        }
        __syncthreads();
        // final top-8 (fp32 desc, index asc), softmax, scatter
        if (t < 32) {
            int rr = t;
            float vv[12]; int ii[12];
            #pragma unroll
            for (int c = 0; c < 12; ++c) { vv[c] = cs[rr][c]; ii[c] = cidx[rr][c]; }
            float fv[8]; int fi[8];
            #pragma unroll
            for (int s = 0; s < 8; ++s) {
                float bv = -INFINITY; int bi = 0x7fffffff; int bc = 0;
                #pragma unroll
                for (int c = 0; c < 12; ++c) {
                    if (vv[c] > bv || (vv[c] == bv && ii[c] < bi)) { bv = vv[c]; bi = ii[c]; bc = c; }
                }
                vv[bc] = -INFINITY;
                fv[s] = bv; fi[s] = bi;
            }
            float m = fv[0];
            float e0[8]; float sum = 0.f;
            #pragma unroll
            for (int s = 0; s < 8; ++s) { e0[s] = __expf(fv[s] - m); sum += e0[s]; }
            float inv = 1.0f / sum;
            int grow = bb * 32 + rr;
            float* awrow = aw + (((size_t)(b * HH + h) * LL) + (size_t)qt * 64 + grow) * LL;
            #pragma unroll
            for (int s = 0; s < 8; ++s) {
                float w8 = e0[s] * inv;
                awrow[fi[s]] = w8;
                wrow[grow][s] = w8; wix[grow][s] = fi[s];
            }
        }
    }
    __syncthreads();

    const float* vbase = v + ((size_t)b * LL) * DD + h * 64;
    #pragma unroll
    for (int i = 0; i < 4; ++i) {
        int id = i * 256 + t;
        int row = id >> 4, seg = id & 15;
        f32x4 acc = {0.f, 0.f, 0.f, 0.f};
        #pragma unroll
        for (int s = 0; s < 8; ++s) {
            float ws = wrow[row][s];
            f32x4 vvv = *(const f32x4*)(vbase + (size_t)wix[row][s] * DD + seg * 4);
            acc[0] = fmaf(ws, vvv[0], acc[0]);
            acc[1] = fmaf(ws, vvv[1], acc[1]);
            acc[2] = fmaf(ws, vvv[2], acc[2]);
            acc[3] = fmaf(ws, vvv[3], acc[3]);
        }
        *(f32x4*)(ctx + ((size_t)(b * LL + qt * 64 + row)) * DD + h * 64 + seg * 4) = acc;
    }
}

// ---------------------------------------------------------------------------
// Projection, workspace path (NO aliasing: ctx in d_ws, out in d_out).
__global__ __launch_bounds__(256) void linear_ws_kernel(
    const float* __restrict__ ctx, const float* __restrict__ w,
    const float* __restrict__ bias, float* __restrict__ out)
{
    const int bid  = blockIdx.x;
    const int nb   = bid & 15, mb = bid >> 4;
    const int t    = threadIdx.x;
    const int wv   = t >> 6;
    const int lane = t & 63;
    const int li   = lane & 15;
    const int quad = lane >> 4;

    __shared__ u16 bhi[8192], blo[8192];   // 32 KB

    f32x4 acc0 = {0.f,0.f,0.f,0.f}, acc1 = {0.f,0.f,0.f,0.f},
          acc2 = {0.f,0.f,0.f,0.f}, acc3 = {0.f,0.f,0.f,0.f};
    const float* arow = ctx + (size_t)(mb * 64 + wv * 16 + li) * DD;

    for (int kc = 0; kc < 8; ++kc) {
        __syncthreads();
        #pragma unroll
        for (int j = 0; j < 4; ++j) {
            int f   = j * 256 + t;
            int col = f >> 4;
            int c   = (f >> 2) & 3;
            int qd  = f & 3;
            const float* src = w + (size_t)(nb * 64 + col) * DD + kc * 128 + c * 32 + qd * 8;
            float x[8];
            *(f32x4*)x       = *(const f32x4*)src;
            *(f32x4*)(x + 4) = *(const f32x4*)(src + 4);
            bf16x8 h8, l8;
            #pragma unroll
            for (int e = 0; e < 8; ++e) { short hh, ll; splitbf(x[e], hh, ll); h8[e] = hh; l8[e] = ll; }
            int off = (((col >> 4) * 4 + c) << 9) + (qd << 7) + ((col & 15) << 3);
            *(bf16x8*)&bhi[off] = h8;
            *(bf16x8*)&blo[off] = l8;
        }
        __syncthreads();

        bf16x8 ah[4], al[4];
        #pragma unroll
        for (int c = 0; c < 4; ++c) {
            float x[8];
            *(f32x4*)x       = *(const f32x4*)(arow + kc * 128 + c * 32 + quad * 8);
            *(f32x4*)(x + 4) = *(const f32x4*)(arow + kc * 128 + c * 32 + quad * 8 + 4);
            #pragma unroll
            for (int e = 0; e < 8; ++e) { short hh, ll; splitbf(x[e], hh, ll); ah[c][e] = hh; al[c][e] = ll; }
        }
        #pragma unroll
        for (int c = 0; c < 4; ++c) {
            bf16x8 bh0 = *(bf16x8*)&bhi[(( 0 + c) << 9) + (lane << 3)];
            bf16x8 bl0 = *(bf16x8*)&blo[(( 0 + c) << 9) + (lane << 3)];
            bf16x8 bh1 = *(bf16x8*)&bhi[(( 4 + c) << 9) + (lane << 3)];
            bf16x8 bl1 = *(bf16x8*)&blo[(( 4 + c) << 9) + (lane << 3)];
            bf16x8 bh2 = *(bf16x8*)&bhi[(( 8 + c) << 9) + (lane << 3)];
            bf16x8 bl2 = *(bf16x8*)&blo[(( 8 + c) << 9) + (lane << 3)];
            bf16x8 bh3 = *(bf16x8*)&bhi[((12 + c) << 9) + (lane << 3)];
            bf16x8 bl3 = *(bf16x8*)&blo[((12 + c) << 9) + (lane << 3)];
            acc0 = __builtin_amdgcn_mfma_f32_16x16x32_bf16(ah[c], bh0, acc0, 0, 0, 0);
            acc0 = __builtin_amdgcn_mfma_f32_16x16x32_bf16(ah[c], bl0, acc0, 0, 0, 0);
            acc0 = __builtin_amdgcn_mfma_f32_16x16x32_bf16(al[c], bh0, acc0, 0, 0, 0);
            acc1 = __builtin_amdgcn_mfma_f32_16x16x32_bf16(ah[c], bh1, acc1, 0, 0, 0);
            acc1 = __builtin_amdgcn_mfma_f32_16x16x32_bf16(ah[c], bl1, acc1, 0, 0, 0);
            acc1 = __builtin_amdgcn_mfma_f32_16x16x32_bf16(al[c], bh1, acc1, 0, 0, 0);
            acc2 = __builtin_amdgcn_mfma_f32_16x16x32_bf16(ah[c], bh2, acc2, 0, 0, 0);
            acc2 = __builtin_amdgcn_mfma_f32_16x16x32_bf16(ah[c], bl2, acc2, 0, 0, 0);
            acc2 = __builtin_amdgcn_mfma_f32_16x16x32_bf16(al[c], bh2, acc2, 0, 0, 0);
            acc3 = __builtin_amdgcn_mfma_f32_16x16x32_bf16(ah[c], bh3, acc3, 0, 0, 0);
            acc3 = __builtin_amdgcn_mfma_f32_16x16x32_bf16(ah[c], bl3, acc3, 0, 0, 0);
            acc3 = __builtin_amdgcn_mfma_f32_16x16x32_bf16(al[c], bh3, acc3, 0, 0, 0);
        }
    }

    #pragma unroll
    for (int st = 0; st < 4; ++st) {
        f32x4 a = (st == 0) ? acc0 : (st == 1) ? acc1 : (st == 2) ? acc2 : acc3;
        int col = nb * 64 + st * 16 + li;
        float bb2 = bias[col];
        #pragma unroll
        for (int r = 0; r < 4; ++r)
            out[(size_t)(mb * 64 + wv * 16 + quad * 4 + r) * DD + col] = a[r] + bb2;
    }
}

// ---------------------------------------------------------------------------
// Projection, in-place fallback. Each block owns 16 rows exclusively, stages
// them to LDS BEFORE any write, computes the rows' full 1024 output cols.
__global__ __launch_bounds__(256) void linear_inplace_kernel(
    float* io, const float* __restrict__ w, const float* __restrict__ bias)
{
    __shared__ u16 ahi[16384], alo[16384];   // 64 KB
    const int t    = threadIdx.x;
    const int m0   = blockIdx.x * 16;
    const int wv   = t >> 6;
    const int lane = t & 63;
    const int li   = lane & 15;
    const int quad = lane >> 4;

    #pragma unroll
    for (int i = 0; i < 8; ++i) {
        int id  = i * 256 + t;
        int row = id >> 7;
        int c   = (id >> 2) & 31;
        int qd  = id & 3;
        const float* src = io + (size_t)(m0 + row) * DD + c * 32 + qd * 8;
        float x[8];
        *(f32x4*)x       = *(const f32x4*)src;
        *(f32x4*)(x + 4) = *(const f32x4*)(src + 4);
        bf16x8 h8, l8;
        #pragma unroll
        for (int e = 0; e < 8; ++e) { short hh, ll; splitbf(x[e], hh, ll); h8[e] = hh; l8[e] = ll; }
        int off = (c << 9) + (qd << 7) + (row << 3);
        *(bf16x8*)&ahi[off] = h8;
        *(bf16x8*)&alo[off] = l8;
    }
    __syncthreads();

    f32x4 acc[16];
    #pragma unroll
    for (int i = 0; i < 16; ++i) acc[i] = (f32x4){0.f, 0.f, 0.f, 0.f};

    for (int c = 0; c < 32; ++c) {
        bf16x8 ah = *(bf16x8*)&ahi[(c << 9) + (lane << 3)];
        bf16x8 al = *(bf16x8*)&alo[(c << 9) + (lane << 3)];
        #pragma unroll
        for (int sub = 0; sub < 16; ++sub) {
            int col = wv * 256 + sub * 16 + li;
            const float* src = w + (size_t)col * DD + c * 32 + quad * 8;
            float x[8];
            *(f32x4*)x       = *(const f32x4*)src;
            *(f32x4*)(x + 4) = *(const f32x4*)(src + 4);
            bf16x8 bh, bl;
            #pragma unroll
            for (int e = 0; e < 8; ++e) { short hh, ll; splitbf(x[e], hh, ll); bh[e] = hh; bl[e] = ll; }
            acc[sub] = __builtin_amdgcn_mfma_f32_16x16x32_bf16(ah, bh, acc[sub], 0, 0, 0);
            acc[sub] = __builtin_amdgcn_mfma_f32_16x16x32_bf16(ah, bl, acc[sub], 0, 0, 0);
            acc[sub] = __builtin_amdgcn_mfma_f32_16x16x32_bf16(al, bh, acc[sub], 0, 0, 0);
        }
    }

    #pragma unroll
    for (int sub = 0; sub < 16; ++sub) {
        int col = wv * 256 + sub * 16 + li;
        float bb2 = bias[col];
        #pragma unroll
        for (int r = 0; r < 4; ++r)
            io[(size_t)(m0 + quad * 4 + r) * DD + col] = acc[sub][r] + bb2;
    }
}

extern "C" void kernel_launch(void* const* d_in, const int* in_sizes, int n_in,
                              void* d_out, int out_size, void* d_ws, size_t ws_size,
                              hipStream_t stream) {
    const float* q    = (const float*)d_in[0];
    const float* k    = (const float*)d_in[1];
    const float* v    = (const float*)d_in[2];
    const float* w    = (const float*)d_in[3];
    const float* bias = (const float*)d_in[4];

    float* out = (float*)d_out;                  // attn_out [B*L*D]
    float* aw  = out + ATTN_ELEMS;               // attn_weights [B*H*L*L]

    const bool use_ws = (d_ws != nullptr) && (ws_size >= ATTN_ELEMS * sizeof(float));
    float* ctx = use_ws ? (float*)d_ws : out;

    attn_kernel<<<BB * HH * (LL / 64), 256, 0, stream>>>(q, k, v, aw, ctx);
    if (use_ws) {
        linear_ws_kernel<<<(BB * LL / 64) * (DD / 64), 256, 0, stream>>>(ctx, w, bias, out);
    } else {
        linear_inplace_kernel<<<BB * LL / 16, 256, 0, stream>>>(out, w, bias);
    }
}